// Round 16
// baseline (605.943 us; speedup 1.0000x reference)
//
#include <hip/hip_runtime.h>

using u16 = unsigned short;
typedef __attribute__((ext_vector_type(8))) short bf16x8;
typedef __attribute__((ext_vector_type(4))) float f32x4;

#define DEVI __device__ __forceinline__

DEVI float bf2f(u16 u){ union{ unsigned v; float f; } x; x.v = ((unsigned)u)<<16; return x.f; }
DEVI u16 f2bf(float f){ union{ float f; unsigned v; } x; x.f = f;
  unsigned r = x.v + 0x7FFFu + ((x.v>>16)&1u); return (u16)(r>>16); }

DEVI float gelu_f(float x){
  float y = 0.7978845608028654f*(x + 0.044715f*x*x*x);
  y = fminf(fmaxf(y, -30.f), 30.f);
  float e = __expf(2.f*y);
  return 0.5f*x*(1.f + (e-1.f)/(e+1.f));
}

DEVI void gload_lds16(const void* g, void* l){
  __builtin_amdgcn_global_load_lds((const __attribute__((address_space(1))) void*)g,
                                   (__attribute__((address_space(3))) void*)l, 16, 0, 0);
}

#define BARM asm volatile("s_barrier" ::: "memory")
#define LGKM0 asm volatile("s_waitcnt lgkmcnt(0)" ::: "memory")
#define VM8  asm volatile("s_waitcnt vmcnt(8)"  ::: "memory")
#define VM0  asm volatile("s_waitcnt vmcnt(0)"  ::: "memory")

// ---------------- block reduction (sum, sumsq) over 256 threads --------------
DEVI void block_reduce2(float& s1, float& s2, int tid){
  #pragma unroll
  for (int off=1; off<64; off<<=1){ s1 += __shfl_xor(s1, off); s2 += __shfl_xor(s2, off); }
  __shared__ float red[8];
  int wid = tid>>6;
  if ((tid&63)==0){ red[wid*2]=s1; red[wid*2+1]=s2; }
  __syncthreads();
  s1 = red[0]+red[2]+red[4]+red[6];
  s2 = red[1]+red[3]+red[5]+red[7];
}

DEVI void ln_row(const float* x, const float* w, const float* b, u16* out, int row, int tid){
  float4 v = ((const float4*)(x + (size_t)row*1024))[tid];
  float s1 = v.x+v.y+v.z+v.w;
  float s2 = v.x*v.x+v.y*v.y+v.z*v.z+v.w*v.w;
  block_reduce2(s1,s2,tid);
  float mean = s1*(1.f/1024.f);
  float var  = s2*(1.f/1024.f) - mean*mean;
  float inv  = rsqrtf(var + 1e-5f);
  float4 wv = ((const float4*)w)[tid];
  float4 bv = ((const float4*)b)[tid];
  ushort4 o;
  o.x = f2bf(wv.x*((v.x-mean)*inv)+bv.x);
  o.y = f2bf(wv.y*((v.y-mean)*inv)+bv.y);
  o.z = f2bf(wv.z*((v.z-mean)*inv)+bv.z);
  o.w = f2bf(wv.w*((v.w-mean)*inv)+bv.w);
  ((ushort4*)(out + (size_t)row*1024))[tid] = o;
}

// ------ fused front kernel: six weight conversions + LN1, one launch ---------
DEVI void wconv_tile(const float* in, u16* out, int R, int C, int cx, int ry){
  __shared__ u16 t[32][132];
  const int c0 = cx*32, r0 = ry*128;
  const int tid = threadIdx.x;
  const int cl = tid & 31, rl = tid >> 5;
  #pragma unroll
  for (int i=0;i<16;i++){
    int r = rl + i*8;
    t[cl][r] = f2bf(in[(size_t)(r0+r)*C + (c0+cl)]);
  }
  __syncthreads();
  const int cc = tid >> 3, q = tid & 7;
  #pragma unroll
  for (int j=0;j<4;j++){
    int rj = q*4 + j*32;
    ushort4 v;
    v.x = t[cc][rj];   v.y = t[cc][rj+1];
    v.z = t[cc][rj+2]; v.w = t[cc][rj+3];
    *(ushort4*)&out[(size_t)(c0+cc)*R + r0 + rj] = v;
  }
}

__global__ __launch_bounds__(256) void front_kernel(
    const float* __restrict__ pw,  u16* __restrict__ pwt,
    const float* __restrict__ fw1, u16* __restrict__ w1t,
    const float* __restrict__ fw2, u16* __restrict__ w2t,
    const float* __restrict__ Wq,  u16* __restrict__ wqt,
    const float* __restrict__ Wk,  u16* __restrict__ wkt,
    const float* __restrict__ Wv,  u16* __restrict__ wvt,
    const float* __restrict__ x,   const float* __restrict__ ln1w,
    const float* __restrict__ ln1b, u16* __restrict__ xn){
  int b = blockIdx.x;
  if (b < 8000){
    wconv_tile(pw, pwt, 1024, 32000, b>>3, b&7);
  } else if (b < 9024){
    int i = b - 8000;
    wconv_tile(fw1, w1t, 1024, 4096, i>>3, i&7);
  } else if (b < 10048){
    int i = b - 9024;
    wconv_tile(fw2, w2t, 4096, 1024, i&31, i>>5);
  } else if (b < 10304){
    int i = b - 10048;
    wconv_tile(Wq, wqt, 1024, 1024, i>>3, i&7);
  } else if (b < 10560){
    int i = b - 10304;
    wconv_tile(Wk, wkt, 1024, 1024, i>>3, i&7);
  } else if (b < 10816){
    int i = b - 10560;
    wconv_tile(Wv, wvt, 1024, 1024, i>>3, i&7);
  } else {
    ln_row(x, ln1w, ln1b, xn, b - 10816, threadIdx.x);
  }
}

__global__ __launch_bounds__(256) void resln_kernel(const float* __restrict__ x,
    const u16* __restrict__ ctx, const float* __restrict__ w, const float* __restrict__ b,
    float* __restrict__ h, u16* __restrict__ hb){
  int row = blockIdx.x, tid = threadIdx.x;
  float4 xv = ((const float4*)(x + (size_t)row*1024))[tid];
  ushort4 cv = ((const ushort4*)(ctx + (size_t)row*1024))[tid];
  float4 hv;
  hv.x = xv.x + bf2f(cv.x); hv.y = xv.y + bf2f(cv.y);
  hv.z = xv.z + bf2f(cv.z); hv.w = xv.w + bf2f(cv.w);
  ((float4*)(h + (size_t)row*1024))[tid] = hv;
  float s1 = hv.x+hv.y+hv.z+hv.w;
  float s2 = hv.x*hv.x+hv.y*hv.y+hv.z*hv.z+hv.w*hv.w;
  block_reduce2(s1,s2,tid);
  float mean = s1*(1.f/1024.f);
  float var  = s2*(1.f/1024.f) - mean*mean;
  float inv  = rsqrtf(var + 1e-5f);
  float4 wv = ((const float4*)w)[tid];
  float4 bv = ((const float4*)b)[tid];
  ushort4 o;
  o.x = f2bf(wv.x*((hv.x-mean)*inv)+bv.x);
  o.y = f2bf(wv.y*((hv.y-mean)*inv)+bv.y);
  o.z = f2bf(wv.z*((hv.z-mean)*inv)+bv.z);
  o.w = f2bf(wv.w*((hv.w-mean)*inv)+bv.w);
  ((ushort4*)(hb + (size_t)row*1024))[tid] = o;
}

// ============ 256x256 / BK=64 GEMM core: 2 barriers + 1 vmcnt per K-tile ======
template<class EpiF>
DEVI void gemm8_core(const u16* __restrict__ A, const u16* __restrict__ Bt,
                     int K, int m0, int n0, EpiF epi){
  __shared__ __align__(16) u16 As[2][16384];
  __shared__ __align__(16) u16 Bs[2][16384];
  const int tid = threadIdx.x;
  const int wid = tid>>6, lane = tid&63;
  const int wr = wid>>2, wc = wid&3;
  const int g = lane>>4, l16 = lane&15;
  const int wq = wid&3;
  const int lr = lane>>3, ls = lane&7;

  f32x4 acc[8][4] = {};

  const u16* aSrc[2][2]; unsigned aDst[2][2];
  #pragma unroll
  for (int qm=0;qm<2;qm++)
    #pragma unroll
    for (int j=0;j<2;j++){
      int r = wr*128 + qm*64 + wq*16 + j*8 + lr;
      aSrc[qm][j] = A + (size_t)(m0 + r)*K + ((ls ^ (r&7))*8);
      aDst[qm][j] = (unsigned)(((wr*128 + qm*64)*8 + (wq*2+j)*64)*16);
    }
  const u16* bSrc[2][2]; unsigned bDst[2][2];
  #pragma unroll
  for (int qn=0;qn<2;qn++)
    #pragma unroll
    for (int j=0;j<2;j++){
      int r = wc*64 + qn*32 + wr*16 + j*8 + lr;
      bSrc[qn][j] = Bt + (size_t)(n0 + r)*K + ((ls ^ (r&7))*8);
      bDst[qn][j] = (unsigned)(((wc*64 + qn*32)*8 + (wr*2+j)*64)*16);
    }

  auto stageAll = [&](int buf, int kc){
    char* ab = (char*)&As[buf][0];
    char* bb = (char*)&Bs[buf][0];
    #pragma unroll
    for (int j=0;j<2;j++) gload_lds16(aSrc[0][j] + kc, ab + aDst[0][j]);
    #pragma unroll
    for (int j=0;j<2;j++) gload_lds16(bSrc[0][j] + kc, bb + bDst[0][j]);
    #pragma unroll
    for (int j=0;j<2;j++) gload_lds16(bSrc[1][j] + kc, bb + bDst[1][j]);
    #pragma unroll
    for (int j=0;j<2;j++) gload_lds16(aSrc[1][j] + kc, ab + aDst[1][j]);
  };
  auto ldA = [&](int buf, int qm, bf16x8 (&a)[4][2]){
    const char* base = (const char*)&As[buf][0];
    #pragma unroll
    for (int i=0;i<4;i++){
      int r = wr*128 + qm*64 + i*16 + l16;
      #pragma unroll
      for (int kk=0;kk<2;kk++)
        a[i][kk] = *(const bf16x8*)(base + r*128 + ((kk*64 + g*16) ^ ((l16&7)<<4)));
    }
  };
  auto ldB = [&](int buf, int qn, bf16x8 (&b)[2][2]){
    const char* base = (const char*)&Bs[buf][0];
    #pragma unroll
    for (int i=0;i<2;i++){
      int r = wc*64 + qn*32 + i*16 + l16;
      #pragma unroll
      for (int kk=0;kk<2;kk++)
        b[i][kk] = *(const bf16x8*)(base + r*128 + ((kk*64 + g*16) ^ ((l16&7)<<4)));
    }
  };
  auto mm = [&](int qm, int qn, bf16x8 (&a)[4][2], bf16x8 (&b)[2][2]){
    __builtin_amdgcn_s_setprio(1);
    #pragma unroll
    for (int i=0;i<4;i++)
      #pragma unroll
      for (int n=0;n<2;n++)
        #pragma unroll
        for (int kk=0;kk<2;kk++)
          acc[qm*4+i][qn*2+n] =
            __builtin_amdgcn_mfma_f32_16x16x32_bf16(a[i][kk], b[n][kk], acc[qm*4+i][qn*2+n], 0,0,0);
    __builtin_amdgcn_s_setprio(0);
  };

  const int NT = K>>6;
  stageAll(0, 0);
  stageAll(1, 64);

  bf16x8 a[4][2], b0[2][2], b1[2][2];
  int cur = 0;
  for (int t=0; t<NT; ++t){
    if (t < NT-1) { VM8; } else { VM0; }
    BARM;
    ldA(cur,0,a); ldB(cur,0,b0); ldB(cur,1,b1);
    mm(0,0,a,b0);
    mm(0,1,a,b1);
    ldA(cur,1,a);
    LGKM0; BARM;
    if (t+2 < NT) stageAll(cur, (t+2)<<6);
    mm(1,0,a,b0);
    mm(1,1,a,b1);
    cur ^= 1;
  }
  BARM;
  epi((char*)&As[0][0], (char*)&Bs[0][0], acc);
}

// ======== 128x128 / BK=64 core, Kstride/Klen split (ffn2 split-K, qkv) ========
template<class EpiF>
DEVI void gemm128_core(const u16* __restrict__ A, const u16* __restrict__ Bt,
                       int Kstride, int Klen, int m0, int n0, EpiF epi){
  __shared__ __align__(16) u16 As[2][8192];
  __shared__ __align__(16) u16 Bs[2][8192];
  const int tid = threadIdx.x;
  const int wid = tid>>6, lane = tid&63;
  const int wr = wid>>1, wc = wid&1;
  const int g = lane>>4, l16 = lane&15;
  const int lr = lane>>3, ls = lane&7;

  f32x4 acc[4][4] = {};

  const u16* aSrc[4]; unsigned aDst[4];
  const u16* bSrc[4];
  #pragma unroll
  for (int j=0;j<4;j++){
    int r = wid*32 + j*8 + lr;
    aSrc[j] = A  + (size_t)(m0 + r)*Kstride + ((ls ^ lr)*8);
    bSrc[j] = Bt + (size_t)(n0 + r)*Kstride + ((ls ^ lr)*8);
    aDst[j] = (unsigned)((wid*32 + j*8)*128);
  }

  auto stageAll = [&](int buf, int kc){
    char* ab = (char*)&As[buf][0];
    char* bb = (char*)&Bs[buf][0];
    #pragma unroll
    for (int j=0;j<4;j++) gload_lds16(aSrc[j] + kc, ab + aDst[j]);
    #pragma unroll
    for (int j=0;j<4;j++) gload_lds16(bSrc[j] + kc, bb + aDst[j]);
  };
  auto ldA = [&](int buf, bf16x8 (&a)[4][2]){
    const char* base = (const char*)&As[buf][0];
    #pragma unroll
    for (int i=0;i<4;i++){
      int r = wr*64 + i*16 + l16;
      #pragma unroll
      for (int kk=0;kk<2;kk++)
        a[i][kk] = *(const bf16x8*)(base + r*128 + ((kk*64 + g*16) ^ ((l16&7)<<4)));
    }
  };
  auto ldB = [&](int buf, bf16x8 (&b)[4][2]){
    const char* base = (const char*)&Bs[buf][0];
    #pragma unroll
    for (int i=0;i<4;i++){
      int r = wc*64 + i*16 + l16;
      #pragma unroll
      for (int kk=0;kk<2;kk++)
        b[i][kk] = *(const bf16x8*)(base + r*128 + ((kk*64 + g*16) ^ ((l16&7)<<4)));
    }
  };

  const int NT = Klen>>6;
  stageAll(0, 0);
  stageAll(1, 64);

  bf16x8 a[4][2], b[4][2];
  int cur = 0;
  for (int t=0; t<NT; ++t){
    if (t < NT-1) { VM8; } else { VM0; }
    BARM;
    ldA(cur, a); ldB(cur, b);
    __builtin_amdgcn_s_setprio(1);
    #pragma unroll
    for (int i=0;i<2;i++)
      #pragma unroll
      for (int n=0;n<4;n++)
        #pragma unroll
        for (int kk=0;kk<2;kk++)
          acc[i][n] = __builtin_amdgcn_mfma_f32_16x16x32_bf16(a[i][kk], b[n][kk], acc[i][n], 0,0,0);
    __builtin_amdgcn_s_setprio(0);
    LGKM0; BARM;
    if (t+2 < NT) stageAll(cur, (t+2)<<6);
    __builtin_amdgcn_s_setprio(1);
    #pragma unroll
    for (int i=2;i<4;i++)
      #pragma unroll
      for (int n=0;n<4;n++)
        #pragma unroll
        for (int kk=0;kk<2;kk++)
          acc[i][n] = __builtin_amdgcn_mfma_f32_16x16x32_bf16(a[i][kk], b[n][kk], acc[i][n], 0,0,0);
    __builtin_amdgcn_s_setprio(0);
    cur ^= 1;
  }
  BARM;
  epi(acc);
}

DEVI int xcd_swz(int id, int nwg){ return (id&7)*(nwg>>3) + (id>>3); }  // nwg%8==0

// proj: R6 XCD mapping; LDS-staged epilogue; nt stores.
__global__ __launch_bounds__(512,2) void proj8_kernel(const u16* __restrict__ hfb,
    const u16* __restrict__ pwt, const float* __restrict__ pb, float* __restrict__ out){
  const int xcd = blockIdx.x & 7, c = blockIdx.x >> 3;
  const int mt = 2*xcd + (c & 1);
  const int nt = c >> 1;
  const int m0 = mt*256, n0 = nt*256;
  gemm8_core(hfb, pwt, 1024, m0, n0,
    [&](char* sA, char* sB, f32x4 (&acc)[8][4]){
      const int tid = threadIdx.x;
      const int wid = tid>>6, lane = tid&63;
      const int wr = wid>>2, wc = wid&3;
      const int g = lane>>4, l16 = lane&15;
      float* ep = (float*)((wid<4 ? sA : sB) + (wid&3)*16384);
      float bb[4];
      #pragma unroll
      for (int nf=0;nf<4;nf++) bb[nf] = pb[n0 + wc*64 + nf*16 + l16];
      #pragma unroll
      for (int p=0;p<2;p++){
        #pragma unroll
        for (int mf4=0;mf4<4;mf4++){
          int mf = p*4 + mf4;
          #pragma unroll
          for (int nf=0;nf<4;nf++){
            #pragma unroll
            for (int r=0;r<4;r++)
              ep[(mf4*16 + g*4 + r)*64 + nf*16 + l16] = acc[mf][nf][r] + bb[nf];
          }
        }
        LGKM0;
        #pragma unroll
        for (int it=0;it<16;it++){
          int rl = it*4 + g;
          f32x4 v = *(const f32x4*)&ep[rl*64 + l16*4];
          int grow = m0 + wr*128 + p*64 + rl;
          __builtin_nontemporal_store(v,
            (f32x4*)&out[(size_t)grow*32000 + n0 + wc*64 + l16*4]);
        }
        LGKM0;
      }
    });
}

__global__ __launch_bounds__(512,2) void ffn1_8_kernel(const u16* __restrict__ hb,
    const u16* __restrict__ w1t, const float* __restrict__ b1, u16* __restrict__ gout){
  int swz = xcd_swz(blockIdx.x, gridDim.x);
  int mt = swz & 15, nt = swz >> 4;
  const int m0 = mt*256, n0 = nt*256;
  gemm8_core(hb, w1t, 1024, m0, n0,
    [&](char*, char*, f32x4 (&acc)[8][4]){
      const int tid = threadIdx.x;
      const int wid = tid>>6, lane = tid&63;
      const int wr = wid>>2, wc = wid&3;
      const int g = lane>>4, l16 = lane&15;
      #pragma unroll
      for (int mf=0;mf<8;mf++)
        #pragma unroll
        for (int nf=0;nf<4;nf++){
          int row = m0 + wr*128 + mf*16 + g*4;
          int col = n0 + wc*64 + nf*16 + l16;
          float bb = b1[col];
          #pragma unroll
          for (int r=0;r<4;r++)
            gout[(size_t)(row+r)*4096 + col] = f2bf(gelu_f(acc[mf][nf][r] + bb));
        }
    });
}

// qkv: 128x128 core, grid 768 (3 mats x 32 mt x 8 nt), 2+ blocks/CU fill.
__global__ __launch_bounds__(256,2) void qkv128_kernel(const u16* __restrict__ xn,
    const u16* __restrict__ wqt, const u16* __restrict__ wkt, const u16* __restrict__ wvt,
    u16* __restrict__ qo, u16* __restrict__ ko, u16* __restrict__ vo){
  const int xcd = blockIdx.x & 7, c = blockIdx.x >> 3;   // c in [0,96)
  const int sel = c >> 5;                                 // 0..2
  const int cc = c & 31;
  const int mt = 4*xcd + (cc & 3);
  const int nt = cc >> 2;                                 // [0,8)
  const u16* Bt = (sel==0)?wqt:((sel==1)?wkt:wvt);
  u16* outp = (sel==0)?qo:((sel==1)?ko:vo);
  const int m0 = mt*128, n0 = nt*128;
  gemm128_core(xn, Bt, 1024, 1024, m0, n0,
    [&](f32x4 (&acc)[4][4]){
      const int tid = threadIdx.x;
      const int wid = tid>>6, lane = tid&63;
      const int wr = wid>>1, wc = wid&1;
      const int g = lane>>4, l16 = lane&15;
      #pragma unroll
      for (int i=0;i<4;i++)
        #pragma unroll
        for (int nf=0;nf<4;nf++){
          int row = m0 + wr*64 + i*16 + g*4;
          int col = n0 + wc*64 + nf*16 + l16;
          #pragma unroll
          for (int r=0;r<4;r++)
            outp[(size_t)(row+r)*1024 + col] = f2bf(acc[i][nf][r]);
        }
    });
}

// ffn2 split-K: grid 512 (2 blocks/CU). ks selects K half; fp32 partials.
__global__ __launch_bounds__(256,2) void ffn2_part_kernel(const u16* __restrict__ gin,
    const u16* __restrict__ w2t, float* __restrict__ p0, float* __restrict__ p1){
  const int xcd = blockIdx.x & 7, c = blockIdx.x >> 3;   // c in [0,64)
  const int ks = c & 1;
  const int cc = c >> 1;                                  // [0,32)
  const int mt = 4*xcd + (cc & 3);
  const int nt = cc >> 2;                                 // [0,8)
  const int m0 = mt*128, n0 = nt*128;
  float* part = ks ? p1 : p0;
  gemm128_core(gin + ks*2048, w2t + ks*2048, 4096, 2048, m0, n0,
    [&](f32x4 (&acc)[4][4]){
      const int tid = threadIdx.x;
      const int wid = tid>>6, lane = tid&63;
      const int wr = wid>>1, wc = wid&1;
      const int g = lane>>4, l16 = lane&15;
      #pragma unroll
      for (int i=0;i<4;i++)
        #pragma unroll
        for (int nf=0;nf<4;nf++){
          int row = m0 + wr*64 + i*16 + g*4;
          int col = n0 + wc*64 + nf*16 + l16;
          #pragma unroll
          for (int r=0;r<4;r++)
            part[(size_t)(row+r)*1024 + col] = acc[i][nf][r];
        }
    });
}

__global__ __launch_bounds__(256) void ffn2_comb_kernel(const float* __restrict__ p0,
    const float* __restrict__ p1, const float* __restrict__ b2,
    const float* __restrict__ h, u16* __restrict__ hfb){
  int row = blockIdx.x, tid = threadIdx.x;
  float4 a = ((const float4*)(p0 + (size_t)row*1024))[tid];
  float4 b = ((const float4*)(p1 + (size_t)row*1024))[tid];
  float4 hv = ((const float4*)(h + (size_t)row*1024))[tid];
  float4 bv = ((const float4*)b2)[tid];
  ushort4 o;
  o.x = f2bf(hv.x + a.x + b.x + bv.x);
  o.y = f2bf(hv.y + a.y + b.y + bv.y);
  o.z = f2bf(hv.z + a.z + b.z + bv.z);
  o.w = f2bf(hv.w + a.w + b.w + bv.w);
  ((ushort4*)(hfb + (size_t)row*1024))[tid] = o;
}

// ---------------- flash attention: T14 async-split + K/V dbuf, longest-first --
__global__ __launch_bounds__(256) void attn_kernel(const u16* __restrict__ q,
    const u16* __restrict__ k, const u16* __restrict__ v, u16* __restrict__ ctx){
  __shared__ u16 Qs[64*64];
  __shared__ u16 Ks[2][64*64], Vt[2][64*64];
  __shared__ u16 Ps[4][16*64];
  const int tid = threadIdx.x, lane = tid&63, wid = tid>>6;
  const int g = lane>>4, l16 = lane&15;
  const int b = blockIdx.x>>4, hh = blockIdx.x&15;
  const int qb = 31 - blockIdx.y;
  const size_t tokbase = (size_t)b*2048;
  const int hoff = hh*64;

  #pragma unroll
  for (int j=0;j<2;j++){
    int c = j*256 + tid;
    int r = c>>3, c8 = c&7;
    uint4 val = *(const uint4*)(q + (tokbase + qb*64 + r)*1024 + hoff + c8*8);
    *(uint4*)((char*)Qs + r*128 + ((c8*16) ^ ((r&7)<<4))) = val;
  }
  uint4 kreg[2], vreg[2];
  #pragma unroll
  for (int j=0;j<2;j++){
    int c = j*256 + tid;
    int r = c>>3, c8 = c&7;
    kreg[j] = *(const uint4*)(k + (tokbase + r)*1024 + hoff + c8*8);
    vreg[j] = *(const uint4*)(v + (tokbase + r)*1024 + hoff + c8*8);
  }
  #pragma unroll
  for (int j=0;j<2;j++){
    int c = j*256 + tid;
    int r = c>>3, c8 = c&7;
    *(uint4*)((char*)&Ks[0][0] + r*128 + ((c8*16) ^ ((r&7)<<4))) = kreg[j];
    union{ uint4 u; u16 s[8]; } uu; uu.u = vreg[j];
    #pragma unroll
    for (int e=0;e<8;e++){
      int d = c8*8 + e;
      *(u16*)((char*)&Vt[0][0] + d*128 + ((r*2) ^ ((d&7)<<4))) = uu.s[e];
    }
  }
  __syncthreads();

  bf16x8 qa[2];
  const int qrow_l = wid*16 + l16;
  #pragma unroll
  for (int kk=0;kk<2;kk++)
    qa[kk] = *(const bf16x8*)((const char*)Qs + qrow_l*128 + ((kk*64 + g*16) ^ ((qrow_l&7)<<4)));

  float m_r[4], l_r[4];
  f32x4 o_acc[4] = {};
  #pragma unroll
  for (int r=0;r<4;r++){ m_r[r] = -1e30f; l_r[r] = 0.f; }

  for (int kt=0; kt<=qb; kt++){
    const int cur = kt&1, nxt = cur^1;
    if (kt < qb){
      const int kv0n = (kt+1)*64;
      #pragma unroll
      for (int j=0;j<2;j++){
        int c = j*256 + tid;
        int r = c>>3, c8 = c&7;
        kreg[j] = *(const uint4*)(k + (tokbase + kv0n + r)*1024 + hoff + c8*8);
        vreg[j] = *(const uint4*)(v + (tokbase + kv0n + r)*1024 + hoff + c8*8);
      }
    }
    const int kv0 = kt*64;
    f32x4 s[4] = {};
    #pragma unroll
    for (int c=0;c<4;c++){
      #pragma unroll
      for (int kk=0;kk<2;kk++){
        int krow = c*16 + l16;
        bf16x8 kb = *(const bf16x8*)((const char*)&Ks[cur][0] + krow*128 + ((kk*64 + g*16) ^ ((krow&7)<<4)));
        s[c] = __builtin_amdgcn_mfma_f32_16x16x32_bf16(qa[kk], kb, s[c], 0,0,0);
      }
    }
    const int qrow0 = qb*64 + wid*16 + g*4;
    float sv[4][4];
    #pragma unroll
    for (int c=0;c<4;c++){
      #pragma unroll
      for (int r=0;r<4;r++){
        float xx = s[c][r] * 0.125f;
        if (kt==qb){
          int kvabs = kv0 + c*16 + l16;
          if (kvabs > qrow0 + r) xx = -1e30f;
        }
        sv[c][r] = xx;
      }
    }
    #pragma unroll
    for (int r=0;r<4;r++){
      float rm = fmaxf(fmaxf(sv[0][r],sv[1][r]),fmaxf(sv[2][r],sv[3][r]));
      #pragma unroll
      for (int off=1; off<16; off<<=1) rm = fmaxf(rm, __shfl_xor(rm, off));
      float mn  = fmaxf(m_r[r], rm);
      float fac = __expf(m_r[r] - mn);
      float rs = 0.f;
      const int prow = g*4 + r;
      #pragma unroll
      for (int c=0;c<4;c++){
        float p = __expf(sv[c][r] - mn);
        rs += p;
        *(u16*)((char*)&Ps[wid][0] + prow*128 + (((c*16+l16)*2) ^ ((prow&7)<<4))) = f2bf(p);
      }
      #pragma unroll
      for (int off=1; off<16; off<<=1) rs += __shfl_xor(rs, off);
      m_r[r] = mn;
      l_r[r] = l_r[r]*fac + rs;
      #pragma unroll
      for (int c=0;c<4;c++) o_acc[c][r] *= fac;
    }
    bf16x8 pa[2];
    #pragma unroll
    for (int kk=0;kk<2;kk++)
      pa[kk] = *(const bf16x8*)((const char*)&Ps[wid][0] + l16*128 + ((kk*64 + g*16) ^ ((l16&7)<<4)));
    #pragma unroll
    for (int c=0;c<4;c++){
      #pragma unroll
      for (int kk=0;kk<2;kk++){
        int vrow = c*16 + l16;
        bf16x8 vb = *(const bf16x8*)((const char*)&Vt[cur][0] + vrow*128 + ((kk*64 + g*16) ^ ((vrow&7)<<4)));
        o_acc[c] = __builtin_amdgcn_mfma_f32_16x16x32_bf16(pa[kk], vb, o_acc[c], 0,0,0);
      }
    }
    if (kt < qb){
      #pragma unroll
      for (int j=0;j<2;j++){
        int c = j*256 + tid;
        int r = c>>3, c8 = c&7;
        *(uint4*)((char*)&Ks[nxt][0] + r*128 + ((c8*16) ^ ((r&7)<<4))) = kreg[j];
        union{ uint4 u; u16 s[8]; } uu; uu.u = vreg[j];
        #pragma unroll
        for (int e=0;e<8;e++){
          int d = c8*8 + e;
          *(u16*)((char*)&Vt[nxt][0] + d*128 + ((r*2) ^ ((d&7)<<4))) = uu.s[e];
        }
      }
    }
    __syncthreads();
  }
  #pragma unroll
  for (int c=0;c<4;c++){
    #pragma unroll
    for (int r=0;r<4;r++){
      float o = o_acc[c][r] / l_r[r];
      size_t tok = tokbase + qb*64 + wid*16 + g*4 + r;
      ctx[tok*1024 + hoff + c*16 + l16] = f2bf(o);
    }
  }
}

// =============================================================================
extern "C" void kernel_launch(void* const* d_in, const int* in_sizes, int n_in,
                              void* d_out, int out_size, void* d_ws, size_t ws_size,
                              hipStream_t stream){
  (void)in_sizes; (void)n_in; (void)out_size; (void)ws_size;
  const float* x    = (const float*)d_in[0];
  const float* Wq   = (const float*)d_in[1];
  const float* Wk   = (const float*)d_in[2];
  const float* Wv   = (const float*)d_in[3];
  const float* ln1w = (const float*)d_in[4];
  const float* ln1b = (const float*)d_in[5];
  const float* ln2w = (const float*)d_in[6];
  const float* ln2b = (const float*)d_in[7];
  const float* fw1  = (const float*)d_in[8];
  const float* fb1  = (const float*)d_in[9];
  const float* fw2  = (const float*)d_in[10];
  const float* fb2  = (const float*)d_in[11];
  const float* pw   = (const float*)d_in[12];
  const float* pb   = (const float*)d_in[13];

  char* ob = (char*)d_out;
  u16* wqt = (u16*)(ob + 0);
  u16* wkt = (u16*)(ob + 2097152);
  u16* wvt = (u16*)(ob + 4194304);
  u16* w1t = (u16*)(ob + 6291456);
  u16* w2t = (u16*)(ob + 14680064);
  u16* xn  = (u16*)(ob + 23068672);
  u16* qbf = (u16*)(ob + 31457280);
  u16* kbf = (u16*)(ob + 39845888);
  u16* vbf = (u16*)(ob + 48234496);
  u16* ctx = (u16*)(ob + 56623104);
  float* h = (float*)(ob + 65011712);
  u16* hb  = (u16*)(ob + 81788928);
  u16* gbuf= (u16*)(ob + 90177536);
  float* p0= (float*)(ob + 134217728);
  float* p1= (float*)(ob + 150994944);

  char* wsb = (char*)d_ws;
  u16* pwt = (u16*)(wsb + 0);
  u16* hfb = (u16*)(wsb + 65536000);

  front_kernel   <<<14912,256,0,stream>>>(pw, pwt, fw1, w1t, fw2, w2t,
                                          Wq, wqt, Wk, wkt, Wv, wvt,
                                          x, ln1w, ln1b, xn);
  qkv128_kernel  <<<768,256,0,stream>>>(xn, wqt, wkt, wvt, qbf, kbf, vbf);
  attn_kernel    <<<dim3(32,32),256,0,stream>>>(qbf, kbf, vbf, ctx);
  resln_kernel   <<<4096,256,0,stream>>>(x, ctx, ln2w, ln2b, h, hb);
  ffn1_8_kernel  <<<256,512,0,stream>>>(hb, w1t, fb1, gbuf);
  ffn2_part_kernel<<<512,256,0,stream>>>(gbuf, w2t, p0, p1);
  ffn2_comb_kernel<<<4096,256,0,stream>>>(p0, p1, fb2, h, hfb);
  proj8_kernel   <<<2000,512,0,stream>>>(hfb, pwt, pb, (float*)d_out);
}

// Round 17
// 581.995 us; speedup vs baseline: 1.0411x; 1.0411x over previous
//
#include <hip/hip_runtime.h>

using u16 = unsigned short;
typedef __attribute__((ext_vector_type(8))) short bf16x8;
typedef __attribute__((ext_vector_type(4))) float f32x4;

#define DEVI __device__ __forceinline__

DEVI float bf2f(u16 u){ union{ unsigned v; float f; } x; x.v = ((unsigned)u)<<16; return x.f; }
DEVI u16 f2bf(float f){ union{ float f; unsigned v; } x; x.f = f;
  unsigned r = x.v + 0x7FFFu + ((x.v>>16)&1u); return (u16)(r>>16); }

DEVI float gelu_f(float x){
  float y = 0.7978845608028654f*(x + 0.044715f*x*x*x);
  y = fminf(fmaxf(y, -30.f), 30.f);
  float e = __expf(2.f*y);
  return 0.5f*x*(1.f + (e-1.f)/(e+1.f));
}

DEVI void gload_lds16(const void* g, void* l){
  __builtin_amdgcn_global_load_lds((const __attribute__((address_space(1))) void*)g,
                                   (__attribute__((address_space(3))) void*)l, 16, 0, 0);
}

#define BARM asm volatile("s_barrier" ::: "memory")
#define LGKM0 asm volatile("s_waitcnt lgkmcnt(0)" ::: "memory")
#define VM8  asm volatile("s_waitcnt vmcnt(8)"  ::: "memory")
#define VM0  asm volatile("s_waitcnt vmcnt(0)"  ::: "memory")

// ---------------- block reduction (sum, sumsq) over 256 threads --------------
DEVI void block_reduce2(float& s1, float& s2, int tid){
  #pragma unroll
  for (int off=1; off<64; off<<=1){ s1 += __shfl_xor(s1, off); s2 += __shfl_xor(s2, off); }
  __shared__ float red[8];
  int wid = tid>>6;
  if ((tid&63)==0){ red[wid*2]=s1; red[wid*2+1]=s2; }
  __syncthreads();
  s1 = red[0]+red[2]+red[4]+red[6];
  s2 = red[1]+red[3]+red[5]+red[7];
}

DEVI void ln_row(const float* x, const float* w, const float* b, u16* out, int row, int tid){
  float4 v = ((const float4*)(x + (size_t)row*1024))[tid];
  float s1 = v.x+v.y+v.z+v.w;
  float s2 = v.x*v.x+v.y*v.y+v.z*v.z+v.w*v.w;
  block_reduce2(s1,s2,tid);
  float mean = s1*(1.f/1024.f);
  float var  = s2*(1.f/1024.f) - mean*mean;
  float inv  = rsqrtf(var + 1e-5f);
  float4 wv = ((const float4*)w)[tid];
  float4 bv = ((const float4*)b)[tid];
  ushort4 o;
  o.x = f2bf(wv.x*((v.x-mean)*inv)+bv.x);
  o.y = f2bf(wv.y*((v.y-mean)*inv)+bv.y);
  o.z = f2bf(wv.z*((v.z-mean)*inv)+bv.z);
  o.w = f2bf(wv.w*((v.w-mean)*inv)+bv.w);
  ((ushort4*)(out + (size_t)row*1024))[tid] = o;
}

// ------ fused front kernel: six weight conversions + LN1, one launch ---------
DEVI void wconv_tile(const float* in, u16* out, int R, int C, int cx, int ry){
  __shared__ u16 t[32][132];
  const int c0 = cx*32, r0 = ry*128;
  const int tid = threadIdx.x;
  const int cl = tid & 31, rl = tid >> 5;
  #pragma unroll
  for (int i=0;i<16;i++){
    int r = rl + i*8;
    t[cl][r] = f2bf(in[(size_t)(r0+r)*C + (c0+cl)]);
  }
  __syncthreads();
  const int cc = tid >> 3, q = tid & 7;
  #pragma unroll
  for (int j=0;j<4;j++){
    int rj = q*4 + j*32;
    ushort4 v;
    v.x = t[cc][rj];   v.y = t[cc][rj+1];
    v.z = t[cc][rj+2]; v.w = t[cc][rj+3];
    *(ushort4*)&out[(size_t)(c0+cc)*R + r0 + rj] = v;
  }
}

__global__ __launch_bounds__(256) void front_kernel(
    const float* __restrict__ pw,  u16* __restrict__ pwt,
    const float* __restrict__ fw1, u16* __restrict__ w1t,
    const float* __restrict__ fw2, u16* __restrict__ w2t,
    const float* __restrict__ Wq,  u16* __restrict__ wqt,
    const float* __restrict__ Wk,  u16* __restrict__ wkt,
    const float* __restrict__ Wv,  u16* __restrict__ wvt,
    const float* __restrict__ x,   const float* __restrict__ ln1w,
    const float* __restrict__ ln1b, u16* __restrict__ xn){
  int b = blockIdx.x;
  if (b < 8000){
    wconv_tile(pw, pwt, 1024, 32000, b>>3, b&7);
  } else if (b < 9024){
    int i = b - 8000;
    wconv_tile(fw1, w1t, 1024, 4096, i>>3, i&7);
  } else if (b < 10048){
    int i = b - 9024;
    wconv_tile(fw2, w2t, 4096, 1024, i&31, i>>5);
  } else if (b < 10304){
    int i = b - 10048;
    wconv_tile(Wq, wqt, 1024, 1024, i>>3, i&7);
  } else if (b < 10560){
    int i = b - 10304;
    wconv_tile(Wk, wkt, 1024, 1024, i>>3, i&7);
  } else if (b < 10816){
    int i = b - 10560;
    wconv_tile(Wv, wvt, 1024, 1024, i>>3, i&7);
  } else {
    ln_row(x, ln1w, ln1b, xn, b - 10816, threadIdx.x);
  }
}

__global__ __launch_bounds__(256) void resln_kernel(const float* __restrict__ x,
    const u16* __restrict__ ctx, const float* __restrict__ w, const float* __restrict__ b,
    float* __restrict__ h, u16* __restrict__ hb){
  int row = blockIdx.x, tid = threadIdx.x;
  float4 xv = ((const float4*)(x + (size_t)row*1024))[tid];
  ushort4 cv = ((const ushort4*)(ctx + (size_t)row*1024))[tid];
  float4 hv;
  hv.x = xv.x + bf2f(cv.x); hv.y = xv.y + bf2f(cv.y);
  hv.z = xv.z + bf2f(cv.z); hv.w = xv.w + bf2f(cv.w);
  ((float4*)(h + (size_t)row*1024))[tid] = hv;
  float s1 = hv.x+hv.y+hv.z+hv.w;
  float s2 = hv.x*hv.x+hv.y*hv.y+hv.z*hv.z+hv.w*hv.w;
  block_reduce2(s1,s2,tid);
  float mean = s1*(1.f/1024.f);
  float var  = s2*(1.f/1024.f) - mean*mean;
  float inv  = rsqrtf(var + 1e-5f);
  float4 wv = ((const float4*)w)[tid];
  float4 bv = ((const float4*)b)[tid];
  ushort4 o;
  o.x = f2bf(wv.x*((hv.x-mean)*inv)+bv.x);
  o.y = f2bf(wv.y*((hv.y-mean)*inv)+bv.y);
  o.z = f2bf(wv.z*((hv.z-mean)*inv)+bv.z);
  o.w = f2bf(wv.w*((hv.w-mean)*inv)+bv.w);
  ((ushort4*)(hb + (size_t)row*1024))[tid] = o;
}

// ============ 256x256 / BK=64 GEMM core: 2 barriers + 1 vmcnt per K-tile ======
template<class EpiF>
DEVI void gemm8_core(const u16* __restrict__ A, const u16* __restrict__ Bt,
                     int K, int m0, int n0, EpiF epi){
  __shared__ __align__(16) u16 As[2][16384];
  __shared__ __align__(16) u16 Bs[2][16384];
  const int tid = threadIdx.x;
  const int wid = tid>>6, lane = tid&63;
  const int wr = wid>>2, wc = wid&3;
  const int g = lane>>4, l16 = lane&15;
  const int wq = wid&3;
  const int lr = lane>>3, ls = lane&7;

  f32x4 acc[8][4] = {};

  const u16* aSrc[2][2]; unsigned aDst[2][2];
  #pragma unroll
  for (int qm=0;qm<2;qm++)
    #pragma unroll
    for (int j=0;j<2;j++){
      int r = wr*128 + qm*64 + wq*16 + j*8 + lr;
      aSrc[qm][j] = A + (size_t)(m0 + r)*K + ((ls ^ (r&7))*8);
      aDst[qm][j] = (unsigned)(((wr*128 + qm*64)*8 + (wq*2+j)*64)*16);
    }
  const u16* bSrc[2][2]; unsigned bDst[2][2];
  #pragma unroll
  for (int qn=0;qn<2;qn++)
    #pragma unroll
    for (int j=0;j<2;j++){
      int r = wc*64 + qn*32 + wr*16 + j*8 + lr;
      bSrc[qn][j] = Bt + (size_t)(n0 + r)*K + ((ls ^ (r&7))*8);
      bDst[qn][j] = (unsigned)(((wc*64 + qn*32)*8 + (wr*2+j)*64)*16);
    }

  auto stageAll = [&](int buf, int kc){
    char* ab = (char*)&As[buf][0];
    char* bb = (char*)&Bs[buf][0];
    #pragma unroll
    for (int j=0;j<2;j++) gload_lds16(aSrc[0][j] + kc, ab + aDst[0][j]);
    #pragma unroll
    for (int j=0;j<2;j++) gload_lds16(bSrc[0][j] + kc, bb + bDst[0][j]);
    #pragma unroll
    for (int j=0;j<2;j++) gload_lds16(bSrc[1][j] + kc, bb + bDst[1][j]);
    #pragma unroll
    for (int j=0;j<2;j++) gload_lds16(aSrc[1][j] + kc, ab + aDst[1][j]);
  };
  auto ldA = [&](int buf, int qm, bf16x8 (&a)[4][2]){
    const char* base = (const char*)&As[buf][0];
    #pragma unroll
    for (int i=0;i<4;i++){
      int r = wr*128 + qm*64 + i*16 + l16;
      #pragma unroll
      for (int kk=0;kk<2;kk++)
        a[i][kk] = *(const bf16x8*)(base + r*128 + ((kk*64 + g*16) ^ ((l16&7)<<4)));
    }
  };
  auto ldB = [&](int buf, int qn, bf16x8 (&b)[2][2]){
    const char* base = (const char*)&Bs[buf][0];
    #pragma unroll
    for (int i=0;i<2;i++){
      int r = wc*64 + qn*32 + i*16 + l16;
      #pragma unroll
      for (int kk=0;kk<2;kk++)
        b[i][kk] = *(const bf16x8*)(base + r*128 + ((kk*64 + g*16) ^ ((l16&7)<<4)));
    }
  };
  auto mm = [&](int qm, int qn, bf16x8 (&a)[4][2], bf16x8 (&b)[2][2]){
    __builtin_amdgcn_s_setprio(1);
    #pragma unroll
    for (int i=0;i<4;i++)
      #pragma unroll
      for (int n=0;n<2;n++)
        #pragma unroll
        for (int kk=0;kk<2;kk++)
          acc[qm*4+i][qn*2+n] =
            __builtin_amdgcn_mfma_f32_16x16x32_bf16(a[i][kk], b[n][kk], acc[qm*4+i][qn*2+n], 0,0,0);
    __builtin_amdgcn_s_setprio(0);
  };

  const int NT = K>>6;
  stageAll(0, 0);
  stageAll(1, 64);

  bf16x8 a[4][2], b0[2][2], b1[2][2];
  int cur = 0;
  for (int t=0; t<NT; ++t){
    if (t < NT-1) { VM8; } else { VM0; }
    BARM;
    ldA(cur,0,a); ldB(cur,0,b0); ldB(cur,1,b1);
    mm(0,0,a,b0);
    mm(0,1,a,b1);
    ldA(cur,1,a);
    LGKM0; BARM;
    if (t+2 < NT) stageAll(cur, (t+2)<<6);
    mm(1,0,a,b0);
    mm(1,1,a,b1);
    cur ^= 1;
  }
  BARM;
  epi((char*)&As[0][0], (char*)&Bs[0][0], acc);
}

// ======== 128x128 / BK=64 core, Kstride/Klen split (for ffn2 split-K) =========
template<class EpiF>
DEVI void gemm128_core(const u16* __restrict__ A, const u16* __restrict__ Bt,
                       int Kstride, int Klen, int m0, int n0, EpiF epi){
  __shared__ __align__(16) u16 As[2][8192];
  __shared__ __align__(16) u16 Bs[2][8192];
  const int tid = threadIdx.x;
  const int wid = tid>>6, lane = tid&63;
  const int wr = wid>>1, wc = wid&1;
  const int g = lane>>4, l16 = lane&15;
  const int lr = lane>>3, ls = lane&7;

  f32x4 acc[4][4] = {};

  const u16* aSrc[4]; unsigned aDst[4];
  const u16* bSrc[4];
  #pragma unroll
  for (int j=0;j<4;j++){
    int r = wid*32 + j*8 + lr;
    aSrc[j] = A  + (size_t)(m0 + r)*Kstride + ((ls ^ lr)*8);
    bSrc[j] = Bt + (size_t)(n0 + r)*Kstride + ((ls ^ lr)*8);
    aDst[j] = (unsigned)((wid*32 + j*8)*128);
  }

  auto stageAll = [&](int buf, int kc){
    char* ab = (char*)&As[buf][0];
    char* bb = (char*)&Bs[buf][0];
    #pragma unroll
    for (int j=0;j<4;j++) gload_lds16(aSrc[j] + kc, ab + aDst[j]);
    #pragma unroll
    for (int j=0;j<4;j++) gload_lds16(bSrc[j] + kc, bb + aDst[j]);
  };
  auto ldA = [&](int buf, bf16x8 (&a)[4][2]){
    const char* base = (const char*)&As[buf][0];
    #pragma unroll
    for (int i=0;i<4;i++){
      int r = wr*64 + i*16 + l16;
      #pragma unroll
      for (int kk=0;kk<2;kk++)
        a[i][kk] = *(const bf16x8*)(base + r*128 + ((kk*64 + g*16) ^ ((l16&7)<<4)));
    }
  };
  auto ldB = [&](int buf, bf16x8 (&b)[4][2]){
    const char* base = (const char*)&Bs[buf][0];
    #pragma unroll
    for (int i=0;i<4;i++){
      int r = wc*64 + i*16 + l16;
      #pragma unroll
      for (int kk=0;kk<2;kk++)
        b[i][kk] = *(const bf16x8*)(base + r*128 + ((kk*64 + g*16) ^ ((l16&7)<<4)));
    }
  };

  const int NT = Klen>>6;
  stageAll(0, 0);
  stageAll(1, 64);

  bf16x8 a[4][2], b[4][2];
  int cur = 0;
  for (int t=0; t<NT; ++t){
    if (t < NT-1) { VM8; } else { VM0; }
    BARM;
    ldA(cur, a); ldB(cur, b);
    __builtin_amdgcn_s_setprio(1);
    #pragma unroll
    for (int i=0;i<2;i++)
      #pragma unroll
      for (int n=0;n<4;n++)
        #pragma unroll
        for (int kk=0;kk<2;kk++)
          acc[i][n] = __builtin_amdgcn_mfma_f32_16x16x32_bf16(a[i][kk], b[n][kk], acc[i][n], 0,0,0);
    __builtin_amdgcn_s_setprio(0);
    LGKM0; BARM;
    if (t+2 < NT) stageAll(cur, (t+2)<<6);
    __builtin_amdgcn_s_setprio(1);
    #pragma unroll
    for (int i=2;i<4;i++)
      #pragma unroll
      for (int n=0;n<4;n++)
        #pragma unroll
        for (int kk=0;kk<2;kk++)
          acc[i][n] = __builtin_amdgcn_mfma_f32_16x16x32_bf16(a[i][kk], b[n][kk], acc[i][n], 0,0,0);
    __builtin_amdgcn_s_setprio(0);
    cur ^= 1;
  }
  BARM;
  epi(acc);
}

DEVI int xcd_swz(int id, int nwg){ return (id&7)*(nwg>>3) + (id>>3); }  // nwg%8==0

// proj: R6 XCD mapping; LDS-staged epilogue; nt stores.
__global__ __launch_bounds__(512,2) void proj8_kernel(const u16* __restrict__ hfb,
    const u16* __restrict__ pwt, const float* __restrict__ pb, float* __restrict__ out){
  const int xcd = blockIdx.x & 7, c = blockIdx.x >> 3;
  const int mt = 2*xcd + (c & 1);
  const int nt = c >> 1;
  const int m0 = mt*256, n0 = nt*256;
  gemm8_core(hfb, pwt, 1024, m0, n0,
    [&](char* sA, char* sB, f32x4 (&acc)[8][4]){
      const int tid = threadIdx.x;
      const int wid = tid>>6, lane = tid&63;
      const int wr = wid>>2, wc = wid&3;
      const int g = lane>>4, l16 = lane&15;
      float* ep = (float*)((wid<4 ? sA : sB) + (wid&3)*16384);
      float bb[4];
      #pragma unroll
      for (int nf=0;nf<4;nf++) bb[nf] = pb[n0 + wc*64 + nf*16 + l16];
      #pragma unroll
      for (int p=0;p<2;p++){
        #pragma unroll
        for (int mf4=0;mf4<4;mf4++){
          int mf = p*4 + mf4;
          #pragma unroll
          for (int nf=0;nf<4;nf++){
            #pragma unroll
            for (int r=0;r<4;r++)
              ep[(mf4*16 + g*4 + r)*64 + nf*16 + l16] = acc[mf][nf][r] + bb[nf];
          }
        }
        LGKM0;
        #pragma unroll
        for (int it=0;it<16;it++){
          int rl = it*4 + g;
          f32x4 v = *(const f32x4*)&ep[rl*64 + l16*4];
          int grow = m0 + wr*128 + p*64 + rl;
          __builtin_nontemporal_store(v,
            (f32x4*)&out[(size_t)grow*32000 + n0 + wc*64 + l16*4]);
        }
        LGKM0;
      }
    });
}

__global__ __launch_bounds__(512,2) void ffn1_8_kernel(const u16* __restrict__ hb,
    const u16* __restrict__ w1t, const float* __restrict__ b1, u16* __restrict__ gout){
  int swz = xcd_swz(blockIdx.x, gridDim.x);
  int mt = swz & 15, nt = swz >> 4;
  const int m0 = mt*256, n0 = nt*256;
  gemm8_core(hb, w1t, 1024, m0, n0,
    [&](char*, char*, f32x4 (&acc)[8][4]){
      const int tid = threadIdx.x;
      const int wid = tid>>6, lane = tid&63;
      const int wr = wid>>2, wc = wid&3;
      const int g = lane>>4, l16 = lane&15;
      #pragma unroll
      for (int mf=0;mf<8;mf++)
        #pragma unroll
        for (int nf=0;nf<4;nf++){
          int row = m0 + wr*128 + mf*16 + g*4;
          int col = n0 + wc*64 + nf*16 + l16;
          float bb = b1[col];
          #pragma unroll
          for (int r=0;r<4;r++)
            gout[(size_t)(row+r)*4096 + col] = f2bf(gelu_f(acc[mf][nf][r] + bb));
        }
    });
}

__global__ __launch_bounds__(512,2) void qkv8_kernel(const u16* __restrict__ xn,
    const u16* __restrict__ wqt, const u16* __restrict__ wkt, const u16* __restrict__ wvt,
    u16* __restrict__ qo, u16* __restrict__ ko, u16* __restrict__ vo){
  int swz = xcd_swz(blockIdx.x, gridDim.x);
  int mt = swz & 15, ntt = swz >> 4;
  int sel = ntt >> 2;
  const u16* Bt = (sel==0)?wqt:((sel==1)?wkt:wvt);
  u16* outp = (sel==0)?qo:((sel==1)?ko:vo);
  const int m0 = mt*256, n0 = (ntt&3)*256;
  gemm8_core(xn, Bt, 1024, m0, n0,
    [&](char*, char*, f32x4 (&acc)[8][4]){
      const int tid = threadIdx.x;
      const int wid = tid>>6, lane = tid&63;
      const int wr = wid>>2, wc = wid&3;
      const int g = lane>>4, l16 = lane&15;
      #pragma unroll
      for (int mf=0;mf<8;mf++)
        #pragma unroll
        for (int nf=0;nf<4;nf++){
          int row = m0 + wr*128 + mf*16 + g*4;
          int col = n0 + wc*64 + nf*16 + l16;
          #pragma unroll
          for (int r=0;r<4;r++)
            outp[(size_t)(row+r)*1024 + col] = f2bf(acc[mf][nf][r]);
        }
    });
}

// ffn2 split-K: grid 512 (2 blocks/CU). ks selects K half; fp32 partials.
__global__ __launch_bounds__(256,2) void ffn2_part_kernel(const u16* __restrict__ gin,
    const u16* __restrict__ w2t, float* __restrict__ p0, float* __restrict__ p1){
  const int xcd = blockIdx.x & 7, c = blockIdx.x >> 3;   // c in [0,64)
  const int ks = c & 1;
  const int cc = c >> 1;                                  // [0,32)
  const int mt = 4*xcd + (cc & 3);
  const int nt = cc >> 2;                                 // [0,8)
  const int m0 = mt*128, n0 = nt*128;
  float* part = ks ? p1 : p0;
  gemm128_core(gin + ks*2048, w2t + ks*2048, 4096, 2048, m0, n0,
    [&](f32x4 (&acc)[4][4]){
      const int tid = threadIdx.x;
      const int wid = tid>>6, lane = tid&63;
      const int wr = wid>>1, wc = wid&1;
      const int g = lane>>4, l16 = lane&15;
      #pragma unroll
      for (int i=0;i<4;i++)
        #pragma unroll
        for (int nf=0;nf<4;nf++){
          int row = m0 + wr*64 + i*16 + g*4;
          int col = n0 + wc*64 + nf*16 + l16;
          #pragma unroll
          for (int r=0;r<4;r++)
            part[(size_t)(row+r)*1024 + col] = acc[i][nf][r];
        }
    });
}

__global__ __launch_bounds__(256) void ffn2_comb_kernel(const float* __restrict__ p0,
    const float* __restrict__ p1, const float* __restrict__ b2,
    const float* __restrict__ h, u16* __restrict__ hfb){
  int row = blockIdx.x, tid = threadIdx.x;
  float4 a = ((const float4*)(p0 + (size_t)row*1024))[tid];
  float4 b = ((const float4*)(p1 + (size_t)row*1024))[tid];
  float4 hv = ((const float4*)(h + (size_t)row*1024))[tid];
  float4 bv = ((const float4*)b2)[tid];
  ushort4 o;
  o.x = f2bf(hv.x + a.x + b.x + bv.x);
  o.y = f2bf(hv.y + a.y + b.y + bv.y);
  o.z = f2bf(hv.z + a.z + b.z + bv.z);
  o.w = f2bf(hv.w + a.w + b.w + bv.w);
  ((ushort4*)(hfb + (size_t)row*1024))[tid] = o;
}

// ---------------- flash attention: T14 async-split + K/V dbuf, longest-first --
__global__ __launch_bounds__(256) void attn_kernel(const u16* __restrict__ q,
    const u16* __restrict__ k, const u16* __restrict__ v, u16* __restrict__ ctx){
  __shared__ u16 Qs[64*64];
  __shared__ u16 Ks[2][64*64], Vt[2][64*64];
  __shared__ u16 Ps[4][16*64];
  const int tid = threadIdx.x, lane = tid&63, wid = tid>>6;
  const int g = lane>>4, l16 = lane&15;
  const int b = blockIdx.x>>4, hh = blockIdx.x&15;
  const int qb = 31 - blockIdx.y;
  const size_t tokbase = (size_t)b*2048;
  const int hoff = hh*64;

  #pragma unroll
  for (int j=0;j<2;j++){
    int c = j*256 + tid;
    int r = c>>3, c8 = c&7;
    uint4 val = *(const uint4*)(q + (tokbase + qb*64 + r)*1024 + hoff + c8*8);
    *(uint4*)((char*)Qs + r*128 + ((c8*16) ^ ((r&7)<<4))) = val;
  }
  uint4 kreg[2], vreg[2];
  #pragma unroll
  for (int j=0;j<2;j++){
    int c = j*256 + tid;
    int r = c>>3, c8 = c&7;
    kreg[j] = *(const uint4*)(k + (tokbase + r)*1024 + hoff + c8*8);
    vreg[j] = *(const uint4*)(v + (tokbase + r)*1024 + hoff + c8*8);
  }
  #pragma unroll
  for (int j=0;j<2;j++){
    int c = j*256 + tid;
    int r = c>>3, c8 = c&7;
    *(uint4*)((char*)&Ks[0][0] + r*128 + ((c8*16) ^ ((r&7)<<4))) = kreg[j];
    union{ uint4 u; u16 s[8]; } uu; uu.u = vreg[j];
    #pragma unroll
    for (int e=0;e<8;e++){
      int d = c8*8 + e;
      *(u16*)((char*)&Vt[0][0] + d*128 + ((r*2) ^ ((d&7)<<4))) = uu.s[e];
    }
  }
  __syncthreads();

  bf16x8 qa[2];
  const int qrow_l = wid*16 + l16;
  #pragma unroll
  for (int kk=0;kk<2;kk++)
    qa[kk] = *(const bf16x8*)((const char*)Qs + qrow_l*128 + ((kk*64 + g*16) ^ ((qrow_l&7)<<4)));

  float m_r[4], l_r[4];
  f32x4 o_acc[4] = {};
  #pragma unroll
  for (int r=0;r<4;r++){ m_r[r] = -1e30f; l_r[r] = 0.f; }

  for (int kt=0; kt<=qb; kt++){
    const int cur = kt&1, nxt = cur^1;
    if (kt < qb){
      const int kv0n = (kt+1)*64;
      #pragma unroll
      for (int j=0;j<2;j++){
        int c = j*256 + tid;
        int r = c>>3, c8 = c&7;
        kreg[j] = *(const uint4*)(k + (tokbase + kv0n + r)*1024 + hoff + c8*8);
        vreg[j] = *(const uint4*)(v + (tokbase + kv0n + r)*1024 + hoff + c8*8);
      }
    }
    const int kv0 = kt*64;
    f32x4 s[4] = {};
    #pragma unroll
    for (int c=0;c<4;c++){
      #pragma unroll
      for (int kk=0;kk<2;kk++){
        int krow = c*16 + l16;
        bf16x8 kb = *(const bf16x8*)((const char*)&Ks[cur][0] + krow*128 + ((kk*64 + g*16) ^ ((krow&7)<<4)));
        s[c] = __builtin_amdgcn_mfma_f32_16x16x32_bf16(qa[kk], kb, s[c], 0,0,0);
      }
    }
    const int qrow0 = qb*64 + wid*16 + g*4;
    float sv[4][4];
    #pragma unroll
    for (int c=0;c<4;c++){
      #pragma unroll
      for (int r=0;r<4;r++){
        float xx = s[c][r] * 0.125f;
        if (kt==qb){
          int kvabs = kv0 + c*16 + l16;
          if (kvabs > qrow0 + r) xx = -1e30f;
        }
        sv[c][r] = xx;
      }
    }
    #pragma unroll
    for (int r=0;r<4;r++){
      float rm = fmaxf(fmaxf(sv[0][r],sv[1][r]),fmaxf(sv[2][r],sv[3][r]));
      #pragma unroll
      for (int off=1; off<16; off<<=1) rm = fmaxf(rm, __shfl_xor(rm, off));
      float mn  = fmaxf(m_r[r], rm);
      float fac = __expf(m_r[r] - mn);
      float rs = 0.f;
      const int prow = g*4 + r;
      #pragma unroll
      for (int c=0;c<4;c++){
        float p = __expf(sv[c][r] - mn);
        rs += p;
        *(u16*)((char*)&Ps[wid][0] + prow*128 + (((c*16+l16)*2) ^ ((prow&7)<<4))) = f2bf(p);
      }
      #pragma unroll
      for (int off=1; off<16; off<<=1) rs += __shfl_xor(rs, off);
      m_r[r] = mn;
      l_r[r] = l_r[r]*fac + rs;
      #pragma unroll
      for (int c=0;c<4;c++) o_acc[c][r] *= fac;
    }
    bf16x8 pa[2];
    #pragma unroll
    for (int kk=0;kk<2;kk++)
      pa[kk] = *(const bf16x8*)((const char*)&Ps[wid][0] + l16*128 + ((kk*64 + g*16) ^ ((l16&7)<<4)));
    #pragma unroll
    for (int c=0;c<4;c++){
      #pragma unroll
      for (int kk=0;kk<2;kk++){
        int vrow = c*16 + l16;
        bf16x8 vb = *(const bf16x8*)((const char*)&Vt[cur][0] + vrow*128 + ((kk*64 + g*16) ^ ((vrow&7)<<4)));
        o_acc[c] = __builtin_amdgcn_mfma_f32_16x16x32_bf16(pa[kk], vb, o_acc[c], 0,0,0);
      }
    }
    if (kt < qb){
      #pragma unroll
      for (int j=0;j<2;j++){
        int c = j*256 + tid;
        int r = c>>3, c8 = c&7;
        *(uint4*)((char*)&Ks[nxt][0] + r*128 + ((c8*16) ^ ((r&7)<<4))) = kreg[j];
        union{ uint4 u; u16 s[8]; } uu; uu.u = vreg[j];
        #pragma unroll
        for (int e=0;e<8;e++){
          int d = c8*8 + e;
          *(u16*)((char*)&Vt[nxt][0] + d*128 + ((r*2) ^ ((d&7)<<4))) = uu.s[e];
        }
      }
    }
    __syncthreads();
  }
  #pragma unroll
  for (int c=0;c<4;c++){
    #pragma unroll
    for (int r=0;r<4;r++){
      float o = o_acc[c][r] / l_r[r];
      size_t tok = tokbase + qb*64 + wid*16 + g*4 + r;
      ctx[tok*1024 + hoff + c*16 + l16] = f2bf(o);
    }
  }
}

// =============================================================================
extern "C" void kernel_launch(void* const* d_in, const int* in_sizes, int n_in,
                              void* d_out, int out_size, void* d_ws, size_t ws_size,
                              hipStream_t stream){
  (void)in_sizes; (void)n_in; (void)out_size; (void)ws_size;
  const float* x    = (const float*)d_in[0];
  const float* Wq   = (const float*)d_in[1];
  const float* Wk   = (const float*)d_in[2];
  const float* Wv   = (const float*)d_in[3];
  const float* ln1w = (const float*)d_in[4];
  const float* ln1b = (const float*)d_in[5];
  const float* ln2w = (const float*)d_in[6];
  const float* ln2b = (const float*)d_in[7];
  const float* fw1  = (const float*)d_in[8];
  const float* fb1  = (const float*)d_in[9];
  const float* fw2  = (const float*)d_in[10];
  const float* fb2  = (const float*)d_in[11];
  const float* pw   = (const float*)d_in[12];
  const float* pb   = (const float*)d_in[13];

  char* ob = (char*)d_out;
  u16* wqt = (u16*)(ob + 0);
  u16* wkt = (u16*)(ob + 2097152);
  u16* wvt = (u16*)(ob + 4194304);
  u16* w1t = (u16*)(ob + 6291456);
  u16* w2t = (u16*)(ob + 14680064);
  u16* xn  = (u16*)(ob + 23068672);
  u16* qbf = (u16*)(ob + 31457280);
  u16* kbf = (u16*)(ob + 39845888);
  u16* vbf = (u16*)(ob + 48234496);
  u16* ctx = (u16*)(ob + 56623104);
  float* h = (float*)(ob + 65011712);
  u16* hb  = (u16*)(ob + 81788928);
  u16* gbuf= (u16*)(ob + 90177536);
  float* p0= (float*)(ob + 134217728);
  float* p1= (float*)(ob + 150994944);

  char* wsb = (char*)d_ws;
  u16* pwt = (u16*)(wsb + 0);
  u16* hfb = (u16*)(wsb + 65536000);

  front_kernel   <<<14912,256,0,stream>>>(pw, pwt, fw1, w1t, fw2, w2t,
                                          Wq, wqt, Wk, wkt, Wv, wvt,
                                          x, ln1w, ln1b, xn);
  qkv8_kernel    <<<192,512,0,stream>>>(xn, wqt, wkt, wvt, qbf, kbf, vbf);
  attn_kernel    <<<dim3(32,32),256,0,stream>>>(qbf, kbf, vbf, ctx);
  resln_kernel   <<<4096,256,0,stream>>>(x, ctx, ln2w, ln2b, h, hb);
  ffn1_8_kernel  <<<256,512,0,stream>>>(hb, w1t, fb1, gbuf);
  ffn2_part_kernel<<<512,256,0,stream>>>(gbuf, w2t, p0, p1);
  ffn2_comb_kernel<<<4096,256,0,stream>>>(p0, p1, fb2, h, hfb);
  proj8_kernel   <<<2000,512,0,stream>>>(hfb, pwt, pb, (float*)d_out);
}